// Round 1
// 275.269 us; speedup vs baseline: 1.3114x; 1.3114x over previous
//
#include <hip/hip_runtime.h>
#include <stdint.h>

// FourierPeriodNet: out[m][c] = sum_f sin(2pi t[m] f[f]) As[c][f] + cos(...) Ac[c][f]
// M = 262144, F = 128, C = 256.
// Round 4: latency-bound fix. Multi-tile blocks (8 x 64 rows), B fragments
// converted to bf16 ONCE per block and held in VGPRs, double-buffered LDS for
// the sin/cos A-tiles (1 barrier/tile), t prefetched one tile ahead.

typedef __bf16 bf16x8 __attribute__((ext_vector_type(8)));
typedef float  floatx4 __attribute__((ext_vector_type(4)));

#define MT    64          // M rows per tile
#define F_    128         // frequencies
#define C_    256         // channels (N)
#define LSTR  264         // LDS row stride in bf16 elems: 256 + 8 pad
#define TPB   8           // tiles per block

__global__ __launch_bounds__(256, 2)
void fourier_fused(const float* __restrict__ t,
                   const float* __restrict__ freqs,
                   const float* __restrict__ amp_sin,
                   const float* __restrict__ amp_cos,
                   float* __restrict__ out)
{
    __shared__ __align__(16) __bf16 Af[2][MT * LSTR];   // 2 x 33792 B

    const int tid  = threadIdx.x;
    const int wave = tid >> 6;       // 0..3 -> 64-col slice of C
    const int lane = tid & 63;
    const int l15  = lane & 15;
    const int quad = lane >> 4;      // 0..3
    const int n0   = wave * 64;

    const int fgrp = tid & 15;       // which octet of 8 freqs (phase 1)
    const int rsub = tid >> 4;       // 0..15 (row-within-16 in phase 1)

    const int tile0 = blockIdx.x * TPB;

    // ---- t prefetch for tile 0 (in flight during freq/B setup) ----
    float tv[4];
    #pragma unroll
    for (int p = 0; p < 4; ++p)
        tv[p] = t[tile0 * MT + p * 16 + rsub];

    // ---- freqs for phase 1 ----
    const float4 f0v = *(const float4*)(freqs + fgrp * 8);
    const float4 f1v = *(const float4*)(freqs + fgrp * 8 + 4);
    const float fr[8] = {f0v.x, f0v.y, f0v.z, f0v.w, f1v.x, f1v.y, f1v.z, f1v.w};

    // ---- B fragments: load fp32 from global once, cvt to bf16, hold in VGPRs.
    // B[k][n] = amp[n][k mod 128]; k<128 -> amp_sin, else amp_cos.
    bf16x8 b[8][4];
    #pragma unroll
    for (int ks = 0; ks < 8; ++ks) {
        const float* __restrict__ amp = (ks < 4) ? amp_sin : amp_cos;
        const int f0 = (ks & 3) * 32 + quad * 8;
        #pragma unroll
        for (int ni = 0; ni < 4; ++ni) {
            const float* p = amp + (n0 + ni * 16 + l15) * F_ + f0;
            const float4 b0 = *(const float4*)(p);
            const float4 b1 = *(const float4*)(p + 4);
            b[ks][ni][0] = (__bf16)b0.x; b[ks][ni][1] = (__bf16)b0.y;
            b[ks][ni][2] = (__bf16)b0.z; b[ks][ni][3] = (__bf16)b0.w;
            b[ks][ni][4] = (__bf16)b1.x; b[ks][ni][5] = (__bf16)b1.y;
            b[ks][ni][6] = (__bf16)b1.z; b[ks][ni][7] = (__bf16)b1.w;
        }
    }

    #pragma unroll 2
    for (int it = 0; it < TPB; ++it) {
        const int m0 = (tile0 + it) * MT;
        __bf16* __restrict__ A = Af[it & 1];

        // ---- prefetch next tile's t (latency hides under trans + MFMA) ----
        float tvn[4];
        {
            const int mb = (it + 1 < TPB) ? (m0 + MT) : tile0 * MT;
            #pragma unroll
            for (int p = 0; p < 4; ++p)
                tvn[p] = t[mb + p * 16 + rsub];
        }

        // ---- phase 1: sin/cos features -> LDS (bf16, [m][k] rows) ----
        #pragma unroll
        for (int pass = 0; pass < 4; ++pass) {
            const int ml = pass * 16 + rsub;
            const float tval = tv[pass];
            bf16x8 sv, cv;
            #pragma unroll
            for (int j = 0; j < 8; ++j) {
                // sin(2*pi*x) = v_sin(fract(x)): HW sin/cos take REVOLUTIONS
                const float r = __builtin_amdgcn_fractf(tval * fr[j]);
                sv[j] = (__bf16)__builtin_amdgcn_sinf(r);
                cv[j] = (__bf16)__builtin_amdgcn_cosf(r);
            }
            *(bf16x8*)&A[ml * LSTR + fgrp * 8]      = sv;   // k = 0..127  : sin
            *(bf16x8*)&A[ml * LSTR + F_ + fgrp * 8] = cv;   // k = 128..255: cos
        }
        __syncthreads();
        // Double-buffer hazard check: phase1(it+2) re-writes this buffer, but a
        // wave reaches it only after barrier(it+1), which any wave still reading
        // in phase2(it) has not passed. One barrier per tile is sufficient.

        // ---- phase 2: MFMA GEMM, K = 256 (sin || cos) ----
        floatx4 acc[4][4];
        #pragma unroll
        for (int mi = 0; mi < 4; ++mi)
            #pragma unroll
            for (int ni = 0; ni < 4; ++ni)
                acc[mi][ni] = (floatx4){0.f, 0.f, 0.f, 0.f};

        #pragma unroll
        for (int ks = 0; ks < 8; ++ks) {
            const int ak = ks * 32 + quad * 8;
            bf16x8 a[4];
            #pragma unroll
            for (int mi = 0; mi < 4; ++mi)
                a[mi] = *(const bf16x8*)&A[(mi * 16 + l15) * LSTR + ak];
            #pragma unroll
            for (int mi = 0; mi < 4; ++mi)
                #pragma unroll
                for (int ni = 0; ni < 4; ++ni)
                    acc[mi][ni] = __builtin_amdgcn_mfma_f32_16x16x32_bf16(
                        a[mi], b[ks][ni], acc[mi][ni], 0, 0, 0);
        }

        // ---- epilogue: D[row = quad*4 + r][col = l15], fp32 out ----
        #pragma unroll
        for (int mi = 0; mi < 4; ++mi) {
            #pragma unroll
            for (int r = 0; r < 4; ++r) {
                const int m = m0 + mi * 16 + quad * 4 + r;
                float* row = out + (size_t)m * C_ + n0 + l15;
                #pragma unroll
                for (int ni = 0; ni < 4; ++ni)
                    row[ni * 16] = acc[mi][ni][r];
            }
        }

        #pragma unroll
        for (int p = 0; p < 4; ++p) tv[p] = tvn[p];
    }
}

extern "C" void kernel_launch(void* const* d_in, const int* in_sizes, int n_in,
                              void* d_out, int out_size, void* d_ws, size_t ws_size,
                              hipStream_t stream) {
    const float* t   = (const float*)d_in[0];
    const float* fq  = (const float*)d_in[1];
    const float* As  = (const float*)d_in[2];
    const float* Ac  = (const float*)d_in[3];
    float* outp      = (float*)d_out;

    const int M = in_sizes[0];               // 262144
    hipLaunchKernelGGL(fourier_fused, dim3(M / (MT * TPB)), dim3(256), 0, stream,
                       t, fq, As, Ac, outp);
}